// Round 2
// baseline (1540.482 us; speedup 1.0000x reference)
//
#include <hip/hip_runtime.h>
#include <hip/hip_bf16.h>
#include <math.h>

#define N_NODES 20000
#define N_EDGES 320000
#define NODE_DIM 64
#define EDGE_DIM 32
#define HID 128
#define HEADS 4
#define HC1 512   // HEADS*HID
#define NEG_SLOPE 0.2f

__device__ __forceinline__ unsigned short f2b(float f) {
  unsigned u = __float_as_uint(f);
  unsigned r = (u + 0x7fffu + ((u >> 16) & 1u)) >> 16;
  return (unsigned short)r;
}
__device__ __forceinline__ float b2f(unsigned short b) {
  return __uint_as_float(((unsigned)b) << 16);
}

// ---------------- CSR build ----------------
__global__ void zero_deg_kernel(int* deg) {
  int i = blockIdx.x * blockDim.x + threadIdx.x;
  if (i < N_NODES) deg[i] = 0;
}

__global__ void deg_count_kernel(const int* __restrict__ dsts, int* __restrict__ deg) {
  int e = blockIdx.x * blockDim.x + threadIdx.x;
  if (e < N_EDGES) atomicAdd(&deg[dsts[e]], 1);
}

__global__ __launch_bounds__(1024) void scan_kernel(
    const int* __restrict__ deg, int* __restrict__ offs, int* __restrict__ cursor)
{
  __shared__ int part[1024];
  int t = threadIdx.x;
  const int C = 20;                 // 1024*20 = 20480 >= N_NODES
  int base = t * C;
  int loc[C]; int s = 0;
  #pragma unroll
  for (int i = 0; i < C; i++) { loc[i] = s; int idx = base + i; s += (idx < N_NODES) ? deg[idx] : 0; }
  part[t] = s;
  __syncthreads();
  for (int off = 1; off < 1024; off <<= 1) {
    int v = (t >= off) ? part[t - off] : 0;
    __syncthreads();
    part[t] += v;
    __syncthreads();
  }
  int pbase = (t > 0) ? part[t - 1] : 0;
  #pragma unroll
  for (int i = 0; i < C; i++) {
    int idx = base + i;
    if (idx < N_NODES) { int o = pbase + loc[i]; offs[idx] = o; cursor[idx] = o; }
  }
  if (t == 1023) offs[N_NODES] = part[1023];
}

__global__ void scatter_kernel(const int* __restrict__ dsts, int* __restrict__ cursor,
                               int* __restrict__ csr) {
  int e = blockIdx.x * blockDim.x + threadIdx.x;
  if (e >= N_EDGES) return;
  int pos = atomicAdd(&cursor[dsts[e]], 1);
  csr[pos] = e;
}

// ---------------- linear1: xl1/xr1 = x@Wl1+bl1 / x@Wr1+br1 ----------------
__global__ __launch_bounds__(256) void linear1_kernel(
    const float* __restrict__ x, const float* __restrict__ Wl,
    const float* __restrict__ bl, const float* __restrict__ Wr,
    const float* __restrict__ br, float* __restrict__ xl, float* __restrict__ xr)
{
  __shared__ float xsT[NODE_DIM][16];
  int n0 = blockIdx.x * 16;
  int t = threadIdx.x;
  {
    int flat = t * 4;
    int i = flat >> 6, k = flat & 63;
    float4 v = *(const float4*)&x[(size_t)(n0 + i) * NODE_DIM + k];
    xsT[k + 0][i] = v.x; xsT[k + 1][i] = v.y; xsT[k + 2][i] = v.z; xsT[k + 3][i] = v.w;
  }
  __syncthreads();
  for (int m = 0; m < 2; m++) {
    const float* W  = m ? Wr : Wl;
    const float* bb = m ? br : bl;
    float* out = m ? xr : xl;
    for (int jh = 0; jh < 2; jh++) {
      int j = t + jh * 256;
      float acc[16];
      #pragma unroll
      for (int i = 0; i < 16; i++) acc[i] = 0.f;
      for (int k = 0; k < NODE_DIM; k++) {
        float w = W[k * HC1 + j];
        float xv[16];
        *(float4*)&xv[0]  = *(const float4*)&xsT[k][0];
        *(float4*)&xv[4]  = *(const float4*)&xsT[k][4];
        *(float4*)&xv[8]  = *(const float4*)&xsT[k][8];
        *(float4*)&xv[12] = *(const float4*)&xsT[k][12];
        #pragma unroll
        for (int i = 0; i < 16; i++) acc[i] = fmaf(xv[i], w, acc[i]);
      }
      float bj = bb[j];
      #pragma unroll
      for (int i = 0; i < 16; i++) out[(size_t)(n0 + i) * HC1 + j] = acc[i] + bj;
    }
  }
}

// ---------------- fused layer 1: edge logits + online softmax + aggregation ----------------
// one wave per destination node; 64 lanes x 8 ch = 512 channels; head = lane>>4
template<bool H1BF>
__global__ __launch_bounds__(256) void fused1_kernel(
    const float* __restrict__ ea, const int* __restrict__ srcs,
    const float* __restrict__ We, const float* __restrict__ att,
    const float* __restrict__ xl, const float* __restrict__ xr,
    const float* __restrict__ bias, const int* __restrict__ offs,
    const int* __restrict__ csr, void* __restrict__ h1out)
{
  __shared__ float Ws[EDGE_DIM * HC1];   // 64KB
  int t = threadIdx.x;
  for (int i = t * 4; i < EDGE_DIM * HC1; i += 1024)
    *(float4*)&Ws[i] = *(const float4*)&We[i];
  __syncthreads();
  int wave = t >> 6, lane = t & 63;
  int n = blockIdx.x * 4 + wave;
  if (n >= N_NODES) return;
  int c0 = lane * 8;
  float atv[8];
  *(float4*)&atv[0] = *(const float4*)&att[c0];
  *(float4*)&atv[4] = *(const float4*)&att[c0 + 4];
  float xrv[8];
  *(float4*)&xrv[0] = *(const float4*)&xr[(size_t)n * HC1 + c0];
  *(float4*)&xrv[4] = *(const float4*)&xr[(size_t)n * HC1 + c0 + 4];
  float accO[8] = {0.f,0.f,0.f,0.f,0.f,0.f,0.f,0.f};
  float m = -3.0e38f, d = 0.f;
  int beg = offs[n], end = offs[n + 1];
  int ev = 0, sv = 0;
  if (lane < 4 && beg + lane < end) { ev = csr[beg + lane]; sv = srcs[ev]; }
  for (int i0 = beg; i0 < end; i0 += 4) {
    int nv = end - i0; if (nv > 4) nv = 4;
    int earr[4], sarr[4];
    #pragma unroll
    for (int j = 0; j < 4; j++) { earr[j] = __shfl(ev, j); sarr[j] = __shfl(sv, j); }
    // issue xl gathers for this chunk (hidden under the ee-GEMM below)
    float xlv[4][8];
    #pragma unroll
    for (int j = 0; j < 4; j++) {
      if (j < nv) {
        const float* p = &xl[(size_t)sarr[j] * HC1 + c0];
        *(float4*)&xlv[j][0] = *(const float4*)p;
        *(float4*)&xlv[j][4] = *(const float4*)(p + 4);
      }
    }
    // prefetch next chunk's indices
    {
      int i1 = i0 + 4;
      if (lane < 4 && i1 + lane < end) { ev = csr[i1 + lane]; sv = srcs[ev]; }
    }
    // ee-GEMM: acc[j][cc] = sum_k ea[e_j,k] * We[k, c0+cc]
    float acc[4][8];
    #pragma unroll
    for (int j = 0; j < 4; j++)
      #pragma unroll
      for (int cc = 0; cc < 8; cc++) acc[j][cc] = 0.f;
    #pragma unroll
    for (int kk = 0; kk < 8; kk++) {
      float av[4][4];
      #pragma unroll
      for (int j = 0; j < 4; j++)
        if (j < nv) *(float4*)&av[j][0] = *(const float4*)&ea[(size_t)earr[j] * EDGE_DIM + kk * 4];
      #pragma unroll
      for (int dk = 0; dk < 4; dk++) {
        float w[8];
        *(float4*)&w[0] = *(const float4*)&Ws[(kk * 4 + dk) * HC1 + c0];
        *(float4*)&w[4] = *(const float4*)&Ws[(kk * 4 + dk) * HC1 + c0 + 4];
        #pragma unroll
        for (int j = 0; j < 4; j++) {
          if (j < nv) {
            #pragma unroll
            for (int cc = 0; cc < 8; cc++) acc[j][cc] = fmaf(av[j][dk], w[cc], acc[j][cc]);
          }
        }
      }
    }
    // tail: logit, online softmax update, accumulate
    #pragma unroll
    for (int j = 0; j < 4; j++) {
      if (j < nv) {
        float pl = 0.f;
        #pragma unroll
        for (int cc = 0; cc < 8; cc++) {
          float z = acc[j][cc] + xlv[j][cc] + xrv[cc];
          float zm = z > 0.f ? z : NEG_SLOPE * z;
          pl = fmaf(zm, atv[cc], pl);
        }
        pl += __shfl_xor(pl, 1);
        pl += __shfl_xor(pl, 2);
        pl += __shfl_xor(pl, 4);
        pl += __shfl_xor(pl, 8);          // 16-lane group = one head
        float mn = fmaxf(m, pl);
        float fs = __expf(m - mn);
        float p  = __expf(pl - mn);
        d = d * fs + p;
        #pragma unroll
        for (int cc = 0; cc < 8; cc++) accO[cc] = fmaf(accO[cc], fs, p * xlv[j][cc]);
        m = mn;
      }
    }
  }
  float invd = d > 0.f ? 1.f / d : 0.f;
  float r[8];
  #pragma unroll
  for (int cc = 0; cc < 8; cc++) {
    float v = accO[cc] * invd + bias[c0 + cc];
    r[cc] = v > 0.f ? v : 0.f;           // relu after conv1
  }
  if (H1BF) {
    unsigned short* hb = (unsigned short*)h1out;
    ushort4 a, b;
    a.x = f2b(r[0]); a.y = f2b(r[1]); a.z = f2b(r[2]); a.w = f2b(r[3]);
    b.x = f2b(r[4]); b.y = f2b(r[5]); b.z = f2b(r[6]); b.w = f2b(r[7]);
    *(ushort4*)&hb[(size_t)n * HC1 + c0]     = a;
    *(ushort4*)&hb[(size_t)n * HC1 + c0 + 4] = b;
  } else {
    float* hf = (float*)h1out;
    *(float4*)&hf[(size_t)n * HC1 + c0]     = *(float4*)&r[0];
    *(float4*)&hf[(size_t)n * HC1 + c0 + 4] = *(float4*)&r[4];
  }
}

// ---------------- linear2: xl2/xr2 = h1@Wl2+bl2 / h1@Wr2+br2 ----------------
template<bool INBF>
__global__ __launch_bounds__(256) void linear2_kernel(
    const void* __restrict__ hin_, const float* __restrict__ Wl,
    const float* __restrict__ bl, const float* __restrict__ Wr,
    const float* __restrict__ br, float* __restrict__ xl, float* __restrict__ xr)
{
  __shared__ float xsT[HC1][16];   // 32KB
  int n0 = blockIdx.x * 16;
  int t = threadIdx.x;
  for (int r = 0; r < 8; r++) {
    int flat = (t + r * 256) * 4;  // 8192 floats
    int i = flat >> 9, k = flat & 511;
    float4 v;
    if (INBF) {
      const unsigned short* hb = (const unsigned short*)hin_;
      ushort4 u = *(const ushort4*)&hb[(size_t)(n0 + i) * HC1 + k];
      v.x = b2f(u.x); v.y = b2f(u.y); v.z = b2f(u.z); v.w = b2f(u.w);
    } else {
      const float* hf = (const float*)hin_;
      v = *(const float4*)&hf[(size_t)(n0 + i) * HC1 + k];
    }
    xsT[k + 0][i] = v.x; xsT[k + 1][i] = v.y; xsT[k + 2][i] = v.z; xsT[k + 3][i] = v.w;
  }
  __syncthreads();
  int m = t >> 7, j = t & 127;
  const float* W = m ? Wr : Wl;
  float bj = (m ? br : bl)[j];
  float* out = m ? xr : xl;
  float acc[16];
  #pragma unroll
  for (int i = 0; i < 16; i++) acc[i] = 0.f;
  for (int k = 0; k < HC1; k++) {
    float w = W[k * HID + j];
    float xv[16];
    *(float4*)&xv[0]  = *(const float4*)&xsT[k][0];
    *(float4*)&xv[4]  = *(const float4*)&xsT[k][4];
    *(float4*)&xv[8]  = *(const float4*)&xsT[k][8];
    *(float4*)&xv[12] = *(const float4*)&xsT[k][12];
    #pragma unroll
    for (int i = 0; i < 16; i++) acc[i] = fmaf(xv[i], w, acc[i]);
  }
  #pragma unroll
  for (int i = 0; i < 16; i++) out[(size_t)(n0 + i) * HID + j] = acc[i] + bj;
}

// ---------------- fused layer 2 + MLP head ----------------
// one wave per node; 64 lanes x 2 ch = 128 channels; single head
__global__ __launch_bounds__(256) void fused2_kernel(
    const float* __restrict__ ea, const int* __restrict__ srcs,
    const float* __restrict__ We, const float* __restrict__ att,
    const float* __restrict__ xl, const float* __restrict__ xr,
    const float* __restrict__ bias, const int* __restrict__ offs,
    const int* __restrict__ csr, const float* __restrict__ Wh1,
    const float* __restrict__ bh1, const float* __restrict__ Wh2,
    const float* __restrict__ bh2, float* __restrict__ out)
{
  __shared__ float Ws[EDGE_DIM * HID];      // 16KB
  __shared__ float Wh1T[64 * 132];          // 33.8KB, transposed+padded
  __shared__ float h2s[4][HID];             // per-wave h2 row
  int t = threadIdx.x;
  for (int i = t * 4; i < EDGE_DIM * HID; i += 1024)
    *(float4*)&Ws[i] = *(const float4*)&We[i];
  for (int i = t; i < HID * 64; i += 256) {
    int k = i >> 6, j = i & 63;
    Wh1T[j * 132 + k] = Wh1[i];
  }
  __syncthreads();
  int wave = t >> 6, lane = t & 63;
  int n = blockIdx.x * 4 + wave;
  if (n >= N_NODES) return;
  int c0 = lane * 2;
  float2 atv = *(const float2*)&att[c0];
  float2 xrv = *(const float2*)&xr[(size_t)n * HID + c0];
  float accO0 = 0.f, accO1 = 0.f;
  float m = -3.0e38f, d = 0.f;
  int beg = offs[n], end = offs[n + 1];
  int ev = 0, sv = 0;
  if (lane < 4 && beg + lane < end) { ev = csr[beg + lane]; sv = srcs[ev]; }
  for (int i0 = beg; i0 < end; i0 += 4) {
    int nv = end - i0; if (nv > 4) nv = 4;
    int earr[4], sarr[4];
    #pragma unroll
    for (int j = 0; j < 4; j++) { earr[j] = __shfl(ev, j); sarr[j] = __shfl(sv, j); }
    float xlv[4][2];
    #pragma unroll
    for (int j = 0; j < 4; j++) {
      if (j < nv) {
        float2 v = *(const float2*)&xl[(size_t)sarr[j] * HID + c0];
        xlv[j][0] = v.x; xlv[j][1] = v.y;
      }
    }
    {
      int i1 = i0 + 4;
      if (lane < 4 && i1 + lane < end) { ev = csr[i1 + lane]; sv = srcs[ev]; }
    }
    float acc[4][2];
    #pragma unroll
    for (int j = 0; j < 4; j++) { acc[j][0] = 0.f; acc[j][1] = 0.f; }
    #pragma unroll
    for (int kk = 0; kk < 8; kk++) {
      float av[4][4];
      #pragma unroll
      for (int j = 0; j < 4; j++)
        if (j < nv) *(float4*)&av[j][0] = *(const float4*)&ea[(size_t)earr[j] * EDGE_DIM + kk * 4];
      #pragma unroll
      for (int dk = 0; dk < 4; dk++) {
        float2 w = *(const float2*)&Ws[(kk * 4 + dk) * HID + c0];
        #pragma unroll
        for (int j = 0; j < 4; j++) {
          if (j < nv) {
            acc[j][0] = fmaf(av[j][dk], w.x, acc[j][0]);
            acc[j][1] = fmaf(av[j][dk], w.y, acc[j][1]);
          }
        }
      }
    }
    #pragma unroll
    for (int j = 0; j < 4; j++) {
      if (j < nv) {
        float z0 = acc[j][0] + xlv[j][0] + xrv.x;
        float z1 = acc[j][1] + xlv[j][1] + xrv.y;
        float m0 = z0 > 0.f ? z0 : NEG_SLOPE * z0;
        float m1 = z1 > 0.f ? z1 : NEG_SLOPE * z1;
        float pl = m0 * atv.x + m1 * atv.y;
        #pragma unroll
        for (int o = 1; o < 64; o <<= 1) pl += __shfl_xor(pl, o);
        float mn = fmaxf(m, pl);
        float fs = __expf(m - mn);
        float p  = __expf(pl - mn);
        d = d * fs + p;
        accO0 = fmaf(accO0, fs, p * xlv[j][0]);
        accO1 = fmaf(accO1, fs, p * xlv[j][1]);
        m = mn;
      }
    }
  }
  float invd = d > 0.f ? 1.f / d : 0.f;
  float v0 = accO0 * invd + bias[c0];
  float v1 = accO1 * invd + bias[c0 + 1];     // no relu after conv2
  // ---- fused MLP head ----
  *(float2*)&h2s[wave][c0] = make_float2(v0, v1);
  asm volatile("s_waitcnt lgkmcnt(0)" ::: "memory");
  float tacc = bh1[lane];
  #pragma unroll 8
  for (int k4 = 0; k4 < HID / 4; k4++) {
    float4 hv = *(const float4*)&h2s[wave][k4 * 4];
    float4 wv = *(const float4*)&Wh1T[lane * 132 + k4 * 4];
    tacc = fmaf(hv.x, wv.x, tacc);
    tacc = fmaf(hv.y, wv.y, tacc);
    tacc = fmaf(hv.z, wv.z, tacc);
    tacc = fmaf(hv.w, wv.w, tacc);
  }
  tacc = tacc > 0.f ? tacc : 0.f;            // relu
  float2 w2v = *(const float2*)&Wh2[lane * 2];
  float p0 = tacc * w2v.x;
  float p1 = tacc * w2v.y;
  #pragma unroll
  for (int o = 1; o < 64; o <<= 1) { p0 += __shfl_xor(p0, o); p1 += __shfl_xor(p1, o); }
  if (lane == 0) {
    float2 o2 = make_float2(p0 + bh2[0], p1 + bh2[1]);
    *(float2*)&out[(size_t)n * 2] = o2;
  }
}

extern "C" void kernel_launch(void* const* d_in, const int* in_sizes, int n_in,
                              void* d_out, int out_size, void* d_ws, size_t ws_size,
                              hipStream_t stream)
{
  (void)in_sizes; (void)n_in; (void)out_size;
  const float* x    = (const float*)d_in[0];
  const int* eidx   = (const int*)d_in[1];
  const float* ea   = (const float*)d_in[2];
  const float* Wl1  = (const float*)d_in[3];
  const float* bl1  = (const float*)d_in[4];
  const float* Wr1  = (const float*)d_in[5];
  const float* br1  = (const float*)d_in[6];
  const float* We1  = (const float*)d_in[7];
  const float* att1 = (const float*)d_in[8];
  const float* bias1= (const float*)d_in[9];
  const float* Wl2  = (const float*)d_in[10];
  const float* bl2  = (const float*)d_in[11];
  const float* Wr2  = (const float*)d_in[12];
  const float* br2  = (const float*)d_in[13];
  const float* We2  = (const float*)d_in[14];
  const float* att2 = (const float*)d_in[15];
  const float* bias2= (const float*)d_in[16];
  const float* Wh1  = (const float*)d_in[17];
  const float* bh1  = (const float*)d_in[18];
  const float* Wh2  = (const float*)d_in[19];
  const float* bh2  = (const float*)d_in[20];
  const int* srcs = eidx;
  const int* dsts = eidx + N_EDGES;
  float* out = (float*)d_out;

  const size_t szBig = (size_t)N_NODES * HC1 * sizeof(float);   // 40.96 MB
  auto aln = [](size_t b) { return (b + 511) & ~(size_t)511; };
  size_t smallSz = aln((size_t)N_NODES * 4) * 2 + aln((size_t)(N_NODES + 1) * 4)
                 + aln((size_t)N_EDGES * 4);
  size_t needF = aln(szBig) * 3 + smallSz + 4096;
  bool useBF = ws_size < needF;    // fall back to bf16 h1 if workspace is tight

  char* p = (char*)d_ws;
  auto alloc = [&](size_t bytes) { char* q = p; p += (bytes + 511) & ~(size_t)511; return q; };
  float* xl1 = (float*)alloc(szBig);
  float* xr1 = (float*)alloc(szBig);          // reused for xl2/xr2 after fused1
  void*  h1  = (void*)alloc(useBF ? szBig / 2 : szBig);
  int* deg    = (int*)alloc((size_t)N_NODES * 4);
  int* offs   = (int*)alloc((size_t)(N_NODES + 1) * 4);
  int* cursor = (int*)alloc((size_t)N_NODES * 4);
  int* csr    = (int*)alloc((size_t)N_EDGES * 4);
  float* xl2 = xr1;
  float* xr2 = xr1 + (size_t)N_NODES * HID;

  // CSR build
  hipLaunchKernelGGL(zero_deg_kernel, dim3((N_NODES + 255) / 256), dim3(256), 0, stream, deg);
  hipLaunchKernelGGL(deg_count_kernel, dim3((N_EDGES + 255) / 256), dim3(256), 0, stream, dsts, deg);
  hipLaunchKernelGGL(scan_kernel, dim3(1), dim3(1024), 0, stream, deg, offs, cursor);
  hipLaunchKernelGGL(scatter_kernel, dim3((N_EDGES + 255) / 256), dim3(256), 0, stream, dsts, cursor, csr);
  // layer 1
  hipLaunchKernelGGL(linear1_kernel, dim3(N_NODES / 16), dim3(256), 0, stream,
                     x, Wl1, bl1, Wr1, br1, xl1, xr1);
  if (useBF)
    hipLaunchKernelGGL((fused1_kernel<true>), dim3(N_NODES / 4), dim3(256), 0, stream,
                       ea, srcs, We1, att1, xl1, xr1, bias1, offs, csr, h1);
  else
    hipLaunchKernelGGL((fused1_kernel<false>), dim3(N_NODES / 4), dim3(256), 0, stream,
                       ea, srcs, We1, att1, xl1, xr1, bias1, offs, csr, h1);
  // layer 2 linears (write into dead xr1 region)
  if (useBF)
    hipLaunchKernelGGL((linear2_kernel<true>), dim3(N_NODES / 16), dim3(256), 0, stream,
                       h1, Wl2, bl2, Wr2, br2, xl2, xr2);
  else
    hipLaunchKernelGGL((linear2_kernel<false>), dim3(N_NODES / 16), dim3(256), 0, stream,
                       h1, Wl2, bl2, Wr2, br2, xl2, xr2);
  // layer 2 fused + head
  hipLaunchKernelGGL(fused2_kernel, dim3(N_NODES / 4), dim3(256), 0, stream,
                     ea, srcs, We2, att2, xl2, xr2, bias2, offs, csr,
                     Wh1, bh1, Wh2, bh2, out);
}

// Round 3
// 801.807 us; speedup vs baseline: 1.9213x; 1.9213x over previous
//
#include <hip/hip_runtime.h>
#include <hip/hip_bf16.h>
#include <math.h>

#define N_NODES 20000
#define N_EDGES 320000
#define NODE_DIM 64
#define EDGE_DIM 32
#define HID 128
#define HEADS 4
#define HC1 512   // HEADS*HID
#define NEG_SLOPE 0.2f

__device__ __forceinline__ unsigned short f2b(float f) {
  unsigned u = __float_as_uint(f);
  unsigned r = (u + 0x7fffu + ((u >> 16) & 1u)) >> 16;
  return (unsigned short)r;
}
__device__ __forceinline__ float b2f(unsigned short b) {
  return __uint_as_float(((unsigned)b) << 16);
}

// ---------------- CSR build ----------------
__global__ void zero_deg_kernel(int* deg) {
  int i = blockIdx.x * blockDim.x + threadIdx.x;
  if (i < N_NODES) deg[i] = 0;
}

__global__ void deg_count_kernel(const int* __restrict__ dsts, int* __restrict__ deg) {
  int e = blockIdx.x * blockDim.x + threadIdx.x;
  if (e < N_EDGES) atomicAdd(&deg[dsts[e]], 1);
}

__global__ __launch_bounds__(1024) void scan_kernel(
    const int* __restrict__ deg, int* __restrict__ offs, int* __restrict__ cursor)
{
  __shared__ int part[1024];
  int t = threadIdx.x;
  const int C = 20;                 // 1024*20 = 20480 >= N_NODES
  int base = t * C;
  int loc[C]; int s = 0;
  #pragma unroll
  for (int i = 0; i < C; i++) { loc[i] = s; int idx = base + i; s += (idx < N_NODES) ? deg[idx] : 0; }
  part[t] = s;
  __syncthreads();
  for (int off = 1; off < 1024; off <<= 1) {
    int v = (t >= off) ? part[t - off] : 0;
    __syncthreads();
    part[t] += v;
    __syncthreads();
  }
  int pbase = (t > 0) ? part[t - 1] : 0;
  #pragma unroll
  for (int i = 0; i < C; i++) {
    int idx = base + i;
    if (idx < N_NODES) { int o = pbase + loc[i]; offs[idx] = o; cursor[idx] = o; }
  }
  if (t == 1023) offs[N_NODES] = part[1023];
}

__global__ void scatter_kernel(const int* __restrict__ dsts, int* __restrict__ cursor,
                               int* __restrict__ csr) {
  int e = blockIdx.x * blockDim.x + threadIdx.x;
  if (e >= N_EDGES) return;
  int pos = atomicAdd(&cursor[dsts[e]], 1);
  csr[pos] = e;
}

// ---------------- linear1 ----------------
__global__ __launch_bounds__(256) void linear1_kernel(
    const float* __restrict__ x, const float* __restrict__ Wl,
    const float* __restrict__ bl, const float* __restrict__ Wr,
    const float* __restrict__ br, float* __restrict__ xl, float* __restrict__ xr)
{
  __shared__ float xsT[NODE_DIM][16];
  int n0 = blockIdx.x * 16;
  int t = threadIdx.x;
  {
    int flat = t * 4;
    int i = flat >> 6, k = flat & 63;
    float4 v = *(const float4*)&x[(size_t)(n0 + i) * NODE_DIM + k];
    xsT[k + 0][i] = v.x; xsT[k + 1][i] = v.y; xsT[k + 2][i] = v.z; xsT[k + 3][i] = v.w;
  }
  __syncthreads();
  for (int m = 0; m < 2; m++) {
    const float* W  = m ? Wr : Wl;
    const float* bb = m ? br : bl;
    float* out = m ? xr : xl;
    for (int jh = 0; jh < 2; jh++) {
      int j = t + jh * 256;
      float acc[16];
      #pragma unroll
      for (int i = 0; i < 16; i++) acc[i] = 0.f;
      for (int k = 0; k < NODE_DIM; k++) {
        float w = W[k * HC1 + j];
        float xv[16];
        *(float4*)&xv[0]  = *(const float4*)&xsT[k][0];
        *(float4*)&xv[4]  = *(const float4*)&xsT[k][4];
        *(float4*)&xv[8]  = *(const float4*)&xsT[k][8];
        *(float4*)&xv[12] = *(const float4*)&xsT[k][12];
        #pragma unroll
        for (int i = 0; i < 16; i++) acc[i] = fmaf(xv[i], w, acc[i]);
      }
      float bj = bb[j];
      #pragma unroll
      for (int i = 0; i < 16; i++) out[(size_t)(n0 + i) * HC1 + j] = acc[i] + bj;
    }
  }
}

// ---------------- fused layer 1 ----------------
// block = 512 threads = 8 waves = 8 nodes sharing Ws.
// lane owns channels {lane*4..+3} (group A) and {256+lane*4..+3} (group B).
// Group A: head = lane>>5 (0 or 1); group B: head 2 or 3. Butterfly xor 1..16.
template<bool H1BF>
__global__ __launch_bounds__(512, 4) void fused1_kernel(
    const float* __restrict__ ea, const int* __restrict__ srcs,
    const float* __restrict__ We, const float* __restrict__ att,
    const float* __restrict__ xl, const float* __restrict__ xr,
    const float* __restrict__ bias, const int* __restrict__ offs,
    const int* __restrict__ csr, void* __restrict__ h1out)
{
  __shared__ float Ws[EDGE_DIM * HC1];   // 64KB
  int t = threadIdx.x;
  for (int i = t * 4; i < EDGE_DIM * HC1; i += 2048)
    *(float4*)&Ws[i] = *(const float4*)&We[i];
  __syncthreads();
  int wave = t >> 6, lane = t & 63;
  int n = blockIdx.x * 8 + wave;         // 2500*8 = 20000 exact
  int ca = lane * 4;                     // group A channels
  int cb = 256 + lane * 4;               // group B channels
  float atA[4], atB[4], xrA[4], xrB[4];
  *(float4*)atA = *(const float4*)&att[ca];
  *(float4*)atB = *(const float4*)&att[cb];
  *(float4*)xrA = *(const float4*)&xr[(size_t)n * HC1 + ca];
  *(float4*)xrB = *(const float4*)&xr[(size_t)n * HC1 + cb];
  float oA[4] = {0.f,0.f,0.f,0.f}, oB[4] = {0.f,0.f,0.f,0.f};
  float mA = -3.0e38f, dA = 0.f, mB = -3.0e38f, dB = 0.f;
  int beg = offs[n], end = offs[n + 1];
  int ev = 0, sv = 0;
  if (lane < 4 && beg + lane < end) { ev = csr[beg + lane]; sv = srcs[ev]; }
  for (int i0 = beg; i0 < end; i0 += 4) {
    int nv = end - i0; if (nv > 4) nv = 4;
    int earr[4], sarr[4];
    #pragma unroll
    for (int j = 0; j < 4; j++) { earr[j] = __shfl(ev, j); sarr[j] = __shfl(sv, j); }
    // gathers issued before GEMM (latency hidden under ~2000 cyc of FMA)
    float xA[4][4], xB[4][4];
    #pragma unroll
    for (int j = 0; j < 4; j++) {
      if (j < nv) {
        const float* p = &xl[(size_t)sarr[j] * HC1];
        *(float4*)&xA[j][0] = *(const float4*)(p + ca);
        *(float4*)&xB[j][0] = *(const float4*)(p + cb);
      } else {
        #pragma unroll
        for (int c = 0; c < 4; c++) { xA[j][c] = 0.f; xB[j][c] = 0.f; }
      }
    }
    // prefetch next chunk's indices
    if (lane < 4 && i0 + 4 + lane < end) { ev = csr[i0 + 4 + lane]; sv = srcs[ev]; }
    // ee-GEMM
    float aA[4][4], aB[4][4];
    #pragma unroll
    for (int j = 0; j < 4; j++)
      #pragma unroll
      for (int c = 0; c < 4; c++) { aA[j][c] = 0.f; aB[j][c] = 0.f; }
    #pragma unroll 1
    for (int kk = 0; kk < 8; kk++) {
      float av[4][4];
      #pragma unroll
      for (int j = 0; j < 4; j++)
        *(float4*)&av[j][0] = *(const float4*)&ea[(size_t)earr[j] * EDGE_DIM + kk * 4];
      #pragma unroll
      for (int dk = 0; dk < 4; dk++) {
        float wA[4], wB[4];
        *(float4*)wA = *(const float4*)&Ws[(kk * 4 + dk) * HC1 + ca];
        *(float4*)wB = *(const float4*)&Ws[(kk * 4 + dk) * HC1 + cb];
        #pragma unroll
        for (int j = 0; j < 4; j++) {
          float a = av[j][dk];
          #pragma unroll
          for (int c = 0; c < 4; c++) {
            aA[j][c] = fmaf(a, wA[c], aA[j][c]);
            aB[j][c] = fmaf(a, wB[c], aB[j][c]);
          }
        }
      }
    }
    // tail: logits (parallel butterflies), defer-max softmax, accumulate
    float plA[4], plB[4];
    #pragma unroll
    for (int j = 0; j < 4; j++) {
      float sA = 0.f, sB = 0.f;
      #pragma unroll
      for (int c = 0; c < 4; c++) {
        float zA = aA[j][c] + xA[j][c] + xrA[c];
        float zB = aB[j][c] + xB[j][c] + xrB[c];
        zA = zA > 0.f ? zA : NEG_SLOPE * zA;
        zB = zB > 0.f ? zB : NEG_SLOPE * zB;
        sA = fmaf(zA, atA[c], sA);
        sB = fmaf(zB, atB[c], sB);
      }
      #pragma unroll
      for (int o = 1; o <= 16; o <<= 1) {
        sA += __shfl_xor(sA, o);
        sB += __shfl_xor(sB, o);
      }
      plA[j] = (j < nv) ? sA : -3.0e38f;
      plB[j] = (j < nv) ? sB : -3.0e38f;
    }
    float cmA = fmaxf(fmaxf(plA[0], plA[1]), fmaxf(plA[2], plA[3]));
    float cmB = fmaxf(fmaxf(plB[0], plB[1]), fmaxf(plB[2], plB[3]));
    float mnA = fmaxf(mA, cmA), mnB = fmaxf(mB, cmB);
    if (__any(mnA > mA + 8.f || mnB > mB + 8.f)) {
      float fsA = __expf(mA - mnA), fsB = __expf(mB - mnB);
      dA *= fsA; dB *= fsB;
      #pragma unroll
      for (int c = 0; c < 4; c++) { oA[c] *= fsA; oB[c] *= fsB; }
      mA = mnA; mB = mnB;
    }
    float pA[4], pB[4];
    #pragma unroll
    for (int j = 0; j < 4; j++) { pA[j] = __expf(plA[j] - mA); pB[j] = __expf(plB[j] - mB); }
    dA += (pA[0] + pA[1]) + (pA[2] + pA[3]);
    dB += (pB[0] + pB[1]) + (pB[2] + pB[3]);
    #pragma unroll
    for (int c = 0; c < 4; c++) {
      oA[c] += (pA[0] * xA[0][c] + pA[1] * xA[1][c]) + (pA[2] * xA[2][c] + pA[3] * xA[3][c]);
      oB[c] += (pB[0] * xB[0][c] + pB[1] * xB[1][c]) + (pB[2] * xB[2][c] + pB[3] * xB[3][c]);
    }
  }
  float iA = dA > 0.f ? 1.f / dA : 0.f;
  float iB = dB > 0.f ? 1.f / dB : 0.f;
  float rA[4], rB[4];
  #pragma unroll
  for (int c = 0; c < 4; c++) {
    float vA = oA[c] * iA + bias[ca + c];
    float vB = oB[c] * iB + bias[cb + c];
    rA[c] = vA > 0.f ? vA : 0.f;         // relu after conv1
    rB[c] = vB > 0.f ? vB : 0.f;
  }
  if (H1BF) {
    unsigned short* hb = (unsigned short*)h1out;
    ushort4 ua, ub;
    ua.x = f2b(rA[0]); ua.y = f2b(rA[1]); ua.z = f2b(rA[2]); ua.w = f2b(rA[3]);
    ub.x = f2b(rB[0]); ub.y = f2b(rB[1]); ub.z = f2b(rB[2]); ub.w = f2b(rB[3]);
    *(ushort4*)&hb[(size_t)n * HC1 + ca] = ua;
    *(ushort4*)&hb[(size_t)n * HC1 + cb] = ub;
  } else {
    float* hf = (float*)h1out;
    *(float4*)&hf[(size_t)n * HC1 + ca] = *(float4*)rA;
    *(float4*)&hf[(size_t)n * HC1 + cb] = *(float4*)rB;
  }
}

// ---------------- linear2 ----------------
template<bool INBF>
__global__ __launch_bounds__(256) void linear2_kernel(
    const void* __restrict__ hin_, const float* __restrict__ Wl,
    const float* __restrict__ bl, const float* __restrict__ Wr,
    const float* __restrict__ br, float* __restrict__ xl, float* __restrict__ xr)
{
  __shared__ float xsT[HC1][16];   // 32KB
  int n0 = blockIdx.x * 16;
  int t = threadIdx.x;
  for (int r = 0; r < 8; r++) {
    int flat = (t + r * 256) * 4;
    int i = flat >> 9, k = flat & 511;
    float4 v;
    if (INBF) {
      const unsigned short* hb = (const unsigned short*)hin_;
      ushort4 u = *(const ushort4*)&hb[(size_t)(n0 + i) * HC1 + k];
      v.x = b2f(u.x); v.y = b2f(u.y); v.z = b2f(u.z); v.w = b2f(u.w);
    } else {
      const float* hf = (const float*)hin_;
      v = *(const float4*)&hf[(size_t)(n0 + i) * HC1 + k];
    }
    xsT[k + 0][i] = v.x; xsT[k + 1][i] = v.y; xsT[k + 2][i] = v.z; xsT[k + 3][i] = v.w;
  }
  __syncthreads();
  int m = t >> 7, j = t & 127;
  const float* W = m ? Wr : Wl;
  float bj = (m ? br : bl)[j];
  float* out = m ? xr : xl;
  float acc[16];
  #pragma unroll
  for (int i = 0; i < 16; i++) acc[i] = 0.f;
  for (int k = 0; k < HC1; k++) {
    float w = W[k * HID + j];
    float xv[16];
    *(float4*)&xv[0]  = *(const float4*)&xsT[k][0];
    *(float4*)&xv[4]  = *(const float4*)&xsT[k][4];
    *(float4*)&xv[8]  = *(const float4*)&xsT[k][8];
    *(float4*)&xv[12] = *(const float4*)&xsT[k][12];
    #pragma unroll
    for (int i = 0; i < 16; i++) acc[i] = fmaf(xv[i], w, acc[i]);
  }
  #pragma unroll
  for (int i = 0; i < 16; i++) out[(size_t)(n0 + i) * HID + j] = acc[i] + bj;
}

// ---------------- fused layer 2 + MLP head ----------------
// block = 512 threads = 8 waves = 8 nodes. lane owns channels {lane, 64+lane}.
__global__ __launch_bounds__(512, 4) void fused2_kernel(
    const float* __restrict__ ea, const int* __restrict__ srcs,
    const float* __restrict__ We, const float* __restrict__ att,
    const float* __restrict__ xl, const float* __restrict__ xr,
    const float* __restrict__ bias, const int* __restrict__ offs,
    const int* __restrict__ csr, const float* __restrict__ Wh1,
    const float* __restrict__ bh1, const float* __restrict__ Wh2,
    const float* __restrict__ bh2, float* __restrict__ out)
{
  __shared__ float Ws[EDGE_DIM * HID];      // 16KB
  __shared__ float Wh1T[64 * 132];          // 33.8KB transposed+padded
  __shared__ float h2s[8][HID];             // 4KB
  int t = threadIdx.x;
  for (int i = t * 4; i < EDGE_DIM * HID; i += 2048)
    *(float4*)&Ws[i] = *(const float4*)&We[i];
  for (int i = t; i < HID * 64; i += 512) {
    int k = i >> 6, j = i & 63;
    Wh1T[j * 132 + k] = Wh1[i];
  }
  __syncthreads();
  int wave = t >> 6, lane = t & 63;
  int n = blockIdx.x * 8 + wave;
  float ata = att[lane], atb = att[64 + lane];
  float xra = xr[(size_t)n * HID + lane], xrb = xr[(size_t)n * HID + 64 + lane];
  float oa = 0.f, ob = 0.f;
  float m = -3.0e38f, d = 0.f;
  int beg = offs[n], end = offs[n + 1];
  int ev = 0, sv = 0;
  if (lane < 4 && beg + lane < end) { ev = csr[beg + lane]; sv = srcs[ev]; }
  for (int i0 = beg; i0 < end; i0 += 4) {
    int nv = end - i0; if (nv > 4) nv = 4;
    int earr[4], sarr[4];
    #pragma unroll
    for (int j = 0; j < 4; j++) { earr[j] = __shfl(ev, j); sarr[j] = __shfl(sv, j); }
    float xa[4], xb[4];
    #pragma unroll
    for (int j = 0; j < 4; j++) {
      if (j < nv) {
        const float* p = &xl[(size_t)sarr[j] * HID];
        xa[j] = p[lane]; xb[j] = p[64 + lane];
      } else { xa[j] = 0.f; xb[j] = 0.f; }
    }
    if (lane < 4 && i0 + 4 + lane < end) { ev = csr[i0 + 4 + lane]; sv = srcs[ev]; }
    float aa[4], ab[4];
    #pragma unroll
    for (int j = 0; j < 4; j++) { aa[j] = 0.f; ab[j] = 0.f; }
    #pragma unroll 1
    for (int kk = 0; kk < 8; kk++) {
      float av[4][4];
      #pragma unroll
      for (int j = 0; j < 4; j++)
        *(float4*)&av[j][0] = *(const float4*)&ea[(size_t)earr[j] * EDGE_DIM + kk * 4];
      #pragma unroll
      for (int dk = 0; dk < 4; dk++) {
        float wA = Ws[(kk * 4 + dk) * HID + lane];
        float wB = Ws[(kk * 4 + dk) * HID + 64 + lane];
        #pragma unroll
        for (int j = 0; j < 4; j++) {
          aa[j] = fmaf(av[j][dk], wA, aa[j]);
          ab[j] = fmaf(av[j][dk], wB, ab[j]);
        }
      }
    }
    float pl[4];
    #pragma unroll
    for (int j = 0; j < 4; j++) {
      float za = aa[j] + xa[j] + xra;
      float zb = ab[j] + xb[j] + xrb;
      za = za > 0.f ? za : NEG_SLOPE * za;
      zb = zb > 0.f ? zb : NEG_SLOPE * zb;
      float s = za * ata + zb * atb;
      #pragma unroll
      for (int o = 1; o < 64; o <<= 1) s += __shfl_xor(s, o);
      pl[j] = (j < nv) ? s : -3.0e38f;
    }
    float cm = fmaxf(fmaxf(pl[0], pl[1]), fmaxf(pl[2], pl[3]));
    float mn = fmaxf(m, cm);
    if (__any(mn > m + 8.f)) {
      float fs = __expf(m - mn);
      d *= fs; oa *= fs; ob *= fs;
      m = mn;
    }
    float p[4];
    #pragma unroll
    for (int j = 0; j < 4; j++) p[j] = __expf(pl[j] - m);
    d += (p[0] + p[1]) + (p[2] + p[3]);
    oa += (p[0] * xa[0] + p[1] * xa[1]) + (p[2] * xa[2] + p[3] * xa[3]);
    ob += (p[0] * xb[0] + p[1] * xb[1]) + (p[2] * xb[2] + p[3] * xb[3]);
  }
  float invd = d > 0.f ? 1.f / d : 0.f;
  float va = oa * invd + bias[lane];
  float vb = ob * invd + bias[64 + lane];   // no relu after conv2
  h2s[wave][lane] = va;
  h2s[wave][64 + lane] = vb;
  asm volatile("s_waitcnt lgkmcnt(0)" ::: "memory");
  float tacc = bh1[lane];
  #pragma unroll 8
  for (int k4 = 0; k4 < HID / 4; k4++) {
    float4 hv = *(const float4*)&h2s[wave][k4 * 4];
    float4 wv = *(const float4*)&Wh1T[lane * 132 + k4 * 4];
    tacc = fmaf(hv.x, wv.x, tacc);
    tacc = fmaf(hv.y, wv.y, tacc);
    tacc = fmaf(hv.z, wv.z, tacc);
    tacc = fmaf(hv.w, wv.w, tacc);
  }
  tacc = tacc > 0.f ? tacc : 0.f;
  float2 w2v = *(const float2*)&Wh2[lane * 2];
  float p0 = tacc * w2v.x;
  float p1 = tacc * w2v.y;
  #pragma unroll
  for (int o = 1; o < 64; o <<= 1) { p0 += __shfl_xor(p0, o); p1 += __shfl_xor(p1, o); }
  if (lane == 0) {
    float2 o2 = make_float2(p0 + bh2[0], p1 + bh2[1]);
    *(float2*)&out[(size_t)n * 2] = o2;
  }
}

extern "C" void kernel_launch(void* const* d_in, const int* in_sizes, int n_in,
                              void* d_out, int out_size, void* d_ws, size_t ws_size,
                              hipStream_t stream)
{
  (void)in_sizes; (void)n_in; (void)out_size;
  const float* x    = (const float*)d_in[0];
  const int* eidx   = (const int*)d_in[1];
  const float* ea   = (const float*)d_in[2];
  const float* Wl1  = (const float*)d_in[3];
  const float* bl1  = (const float*)d_in[4];
  const float* Wr1  = (const float*)d_in[5];
  const float* br1  = (const float*)d_in[6];
  const float* We1  = (const float*)d_in[7];
  const float* att1 = (const float*)d_in[8];
  const float* bias1= (const float*)d_in[9];
  const float* Wl2  = (const float*)d_in[10];
  const float* bl2  = (const float*)d_in[11];
  const float* Wr2  = (const float*)d_in[12];
  const float* br2  = (const float*)d_in[13];
  const float* We2  = (const float*)d_in[14];
  const float* att2 = (const float*)d_in[15];
  const float* bias2= (const float*)d_in[16];
  const float* Wh1  = (const float*)d_in[17];
  const float* bh1  = (const float*)d_in[18];
  const float* Wh2  = (const float*)d_in[19];
  const float* bh2  = (const float*)d_in[20];
  const int* srcs = eidx;
  const int* dsts = eidx + N_EDGES;
  float* out = (float*)d_out;

  const size_t szBig = (size_t)N_NODES * HC1 * sizeof(float);
  auto aln = [](size_t b) { return (b + 511) & ~(size_t)511; };
  size_t smallSz = aln((size_t)N_NODES * 4) * 2 + aln((size_t)(N_NODES + 1) * 4)
                 + aln((size_t)N_EDGES * 4);
  size_t needF = aln(szBig) * 3 + smallSz + 4096;
  bool useBF = ws_size < needF;

  char* p = (char*)d_ws;
  auto alloc = [&](size_t bytes) { char* q = p; p += (bytes + 511) & ~(size_t)511; return q; };
  float* xl1 = (float*)alloc(szBig);
  float* xr1 = (float*)alloc(szBig);          // reused for xl2/xr2 after fused1
  void*  h1  = (void*)alloc(useBF ? szBig / 2 : szBig);
  int* deg    = (int*)alloc((size_t)N_NODES * 4);
  int* offs   = (int*)alloc((size_t)(N_NODES + 1) * 4);
  int* cursor = (int*)alloc((size_t)N_NODES * 4);
  int* csr    = (int*)alloc((size_t)N_EDGES * 4);
  float* xl2 = xr1;
  float* xr2 = xr1 + (size_t)N_NODES * HID;

  hipLaunchKernelGGL(zero_deg_kernel, dim3((N_NODES + 255) / 256), dim3(256), 0, stream, deg);
  hipLaunchKernelGGL(deg_count_kernel, dim3((N_EDGES + 255) / 256), dim3(256), 0, stream, dsts, deg);
  hipLaunchKernelGGL(scan_kernel, dim3(1), dim3(1024), 0, stream, deg, offs, cursor);
  hipLaunchKernelGGL(scatter_kernel, dim3((N_EDGES + 255) / 256), dim3(256), 0, stream, dsts, cursor, csr);
  hipLaunchKernelGGL(linear1_kernel, dim3(N_NODES / 16), dim3(256), 0, stream,
                     x, Wl1, bl1, Wr1, br1, xl1, xr1);
  if (useBF)
    hipLaunchKernelGGL((fused1_kernel<true>), dim3(N_NODES / 8), dim3(512), 0, stream,
                       ea, srcs, We1, att1, xl1, xr1, bias1, offs, csr, h1);
  else
    hipLaunchKernelGGL((fused1_kernel<false>), dim3(N_NODES / 8), dim3(512), 0, stream,
                       ea, srcs, We1, att1, xl1, xr1, bias1, offs, csr, h1);
  if (useBF)
    hipLaunchKernelGGL((linear2_kernel<true>), dim3(N_NODES / 16), dim3(256), 0, stream,
                       h1, Wl2, bl2, Wr2, br2, xl2, xr2);
  else
    hipLaunchKernelGGL((linear2_kernel<false>), dim3(N_NODES / 16), dim3(256), 0, stream,
                       h1, Wl2, bl2, Wr2, br2, xl2, xr2);
  hipLaunchKernelGGL(fused2_kernel, dim3(N_NODES / 8), dim3(512), 0, stream,
                     ea, srcs, We2, att2, xl2, xr2, bias2, offs, csr,
                     Wh1, bh1, Wh2, bh2, out);
}

// Round 4
// 685.648 us; speedup vs baseline: 2.2468x; 1.1694x over previous
//
#include <hip/hip_runtime.h>
#include <hip/hip_bf16.h>
#include <math.h>

#define N_NODES 20000
#define N_EDGES 320000
#define NODE_DIM 64
#define EDGE_DIM 32
#define HID 128
#define HEADS 4
#define HC1 512   // HEADS*HID
#define NEG_SLOPE 0.2f

__device__ __forceinline__ unsigned short f2b(float f) {
  unsigned u = __float_as_uint(f);
  unsigned r = (u + 0x7fffu + ((u >> 16) & 1u)) >> 16;
  return (unsigned short)r;
}
__device__ __forceinline__ float b2f(unsigned short b) {
  return __uint_as_float(((unsigned)b) << 16);
}

// ---------------- CSR build ----------------
__global__ void zero_deg_kernel(int* deg) {
  int i = blockIdx.x * blockDim.x + threadIdx.x;
  if (i < N_NODES) deg[i] = 0;
}

__global__ void deg_count_kernel(const int* __restrict__ dsts, int* __restrict__ deg) {
  int e = blockIdx.x * blockDim.x + threadIdx.x;
  if (e < N_EDGES) atomicAdd(&deg[dsts[e]], 1);
}

__global__ __launch_bounds__(1024) void scan_kernel(
    const int* __restrict__ deg, int* __restrict__ offs, int* __restrict__ cursor)
{
  __shared__ int part[1024];
  int t = threadIdx.x;
  const int C = 20;                 // 1024*20 = 20480 >= N_NODES
  int base = t * C;
  int loc[C]; int s = 0;
  #pragma unroll
  for (int i = 0; i < C; i++) { loc[i] = s; int idx = base + i; s += (idx < N_NODES) ? deg[idx] : 0; }
  part[t] = s;
  __syncthreads();
  for (int off = 1; off < 1024; off <<= 1) {
    int v = (t >= off) ? part[t - off] : 0;
    __syncthreads();
    part[t] += v;
    __syncthreads();
  }
  int pbase = (t > 0) ? part[t - 1] : 0;
  #pragma unroll
  for (int i = 0; i < C; i++) {
    int idx = base + i;
    if (idx < N_NODES) { int o = pbase + loc[i]; offs[idx] = o; cursor[idx] = o; }
  }
  if (t == 1023) offs[N_NODES] = part[1023];
}

__global__ void scatter_kernel(const int* __restrict__ dsts, int* __restrict__ cursor,
                               int* __restrict__ csr) {
  int e = blockIdx.x * blockDim.x + threadIdx.x;
  if (e >= N_EDGES) return;
  int pos = atomicAdd(&cursor[dsts[e]], 1);
  csr[pos] = e;
}

// ---------------- linear1 ----------------
__global__ __launch_bounds__(256) void linear1_kernel(
    const float* __restrict__ x, const float* __restrict__ Wl,
    const float* __restrict__ bl, const float* __restrict__ Wr,
    const float* __restrict__ br, float* __restrict__ xl, float* __restrict__ xr)
{
  __shared__ float xsT[NODE_DIM][16];
  int n0 = blockIdx.x * 16;
  int t = threadIdx.x;
  {
    int flat = t * 4;
    int i = flat >> 6, k = flat & 63;
    float4 v = *(const float4*)&x[(size_t)(n0 + i) * NODE_DIM + k];
    xsT[k + 0][i] = v.x; xsT[k + 1][i] = v.y; xsT[k + 2][i] = v.z; xsT[k + 3][i] = v.w;
  }
  __syncthreads();
  for (int m = 0; m < 2; m++) {
    const float* W  = m ? Wr : Wl;
    const float* bb = m ? br : bl;
    float* out = m ? xr : xl;
    for (int jh = 0; jh < 2; jh++) {
      int j = t + jh * 256;
      float acc[16];
      #pragma unroll
      for (int i = 0; i < 16; i++) acc[i] = 0.f;
      for (int k = 0; k < NODE_DIM; k++) {
        float w = W[k * HC1 + j];
        float xv[16];
        *(float4*)&xv[0]  = *(const float4*)&xsT[k][0];
        *(float4*)&xv[4]  = *(const float4*)&xsT[k][4];
        *(float4*)&xv[8]  = *(const float4*)&xsT[k][8];
        *(float4*)&xv[12] = *(const float4*)&xsT[k][12];
        #pragma unroll
        for (int i = 0; i < 16; i++) acc[i] = fmaf(xv[i], w, acc[i]);
      }
      float bj = bb[j];
      #pragma unroll
      for (int i = 0; i < 16; i++) out[(size_t)(n0 + i) * HC1 + j] = acc[i] + bj;
    }
  }
}

// ---------------- fused layer 1 ----------------
// block = 512 threads = 8 waves = 8 nodes sharing Ws.
// lane owns channels {lane*4..+3} (group A) and {256+lane*4..+3} (group B).
// launch_bounds(512,2): 2 blocks/CU -> 16 waves/CU -> 128-VGPR budget, no spill.
template<bool H1BF>
__global__ __launch_bounds__(512, 2) void fused1_kernel(
    const float* __restrict__ ea, const int* __restrict__ srcs,
    const float* __restrict__ We, const float* __restrict__ att,
    const float* __restrict__ xl, const float* __restrict__ xr,
    const float* __restrict__ bias, const int* __restrict__ offs,
    const int* __restrict__ csr, void* __restrict__ h1out)
{
  __shared__ float Ws[EDGE_DIM * HC1];   // 64KB
  int t = threadIdx.x;
  for (int i = t * 4; i < EDGE_DIM * HC1; i += 2048)
    *(float4*)&Ws[i] = *(const float4*)&We[i];
  __syncthreads();
  int wave = t >> 6, lane = t & 63;
  int n = blockIdx.x * 8 + wave;         // 2500*8 = 20000 exact
  int ca = lane * 4;                     // group A channels
  int cb = 256 + lane * 4;               // group B channels
  float atA[4], atB[4], xrA[4], xrB[4];
  *(float4*)atA = *(const float4*)&att[ca];
  *(float4*)atB = *(const float4*)&att[cb];
  *(float4*)xrA = *(const float4*)&xr[(size_t)n * HC1 + ca];
  *(float4*)xrB = *(const float4*)&xr[(size_t)n * HC1 + cb];
  float oA[4] = {0.f,0.f,0.f,0.f}, oB[4] = {0.f,0.f,0.f,0.f};
  float mA = -3.0e38f, dA = 0.f, mB = -3.0e38f, dB = 0.f;
  int beg = offs[n], end = offs[n + 1];
  int ev = 0, sv = 0;
  if (lane < 4 && beg + lane < end) { ev = csr[beg + lane]; sv = srcs[ev]; }
  for (int i0 = beg; i0 < end; i0 += 4) {
    int nv = end - i0; if (nv > 4) nv = 4;
    int earr[4], sarr[4];
    #pragma unroll
    for (int j = 0; j < 4; j++) { earr[j] = __shfl(ev, j); sarr[j] = __shfl(sv, j); }
    // gathers issued before GEMM (latency hidden under ~2000 cyc of FMA)
    float xA[4][4], xB[4][4];
    #pragma unroll
    for (int j = 0; j < 4; j++) {
      if (j < nv) {
        const float* p = &xl[(size_t)sarr[j] * HC1];
        *(float4*)&xA[j][0] = *(const float4*)(p + ca);
        *(float4*)&xB[j][0] = *(const float4*)(p + cb);
      } else {
        #pragma unroll
        for (int c = 0; c < 4; c++) { xA[j][c] = 0.f; xB[j][c] = 0.f; }
      }
    }
    // prefetch next chunk's indices
    if (lane < 4 && i0 + 4 + lane < end) { ev = csr[i0 + 4 + lane]; sv = srcs[ev]; }
    // ee-GEMM
    float aA[4][4], aB[4][4];
    #pragma unroll
    for (int j = 0; j < 4; j++)
      #pragma unroll
      for (int c = 0; c < 4; c++) { aA[j][c] = 0.f; aB[j][c] = 0.f; }
    #pragma unroll 1
    for (int kk = 0; kk < 8; kk++) {
      float av[4][4];
      #pragma unroll
      for (int j = 0; j < 4; j++)
        *(float4*)&av[j][0] = *(const float4*)&ea[(size_t)earr[j] * EDGE_DIM + kk * 4];
      #pragma unroll
      for (int dk = 0; dk < 4; dk++) {
        float wA[4], wB[4];
        *(float4*)wA = *(const float4*)&Ws[(kk * 4 + dk) * HC1 + ca];
        *(float4*)wB = *(const float4*)&Ws[(kk * 4 + dk) * HC1 + cb];
        #pragma unroll
        for (int j = 0; j < 4; j++) {
          float a = av[j][dk];
          #pragma unroll
          for (int c = 0; c < 4; c++) {
            aA[j][c] = fmaf(a, wA[c], aA[j][c]);
            aB[j][c] = fmaf(a, wB[c], aB[j][c]);
          }
        }
      }
    }
    // tail: logits (parallel butterflies), defer-max softmax, accumulate
    float plA[4], plB[4];
    #pragma unroll
    for (int j = 0; j < 4; j++) {
      float sA = 0.f, sB = 0.f;
      #pragma unroll
      for (int c = 0; c < 4; c++) {
        float zA = aA[j][c] + xA[j][c] + xrA[c];
        float zB = aB[j][c] + xB[j][c] + xrB[c];
        zA = zA > 0.f ? zA : NEG_SLOPE * zA;
        zB = zB > 0.f ? zB : NEG_SLOPE * zB;
        sA = fmaf(zA, atA[c], sA);
        sB = fmaf(zB, atB[c], sB);
      }
      #pragma unroll
      for (int o = 1; o <= 16; o <<= 1) {
        sA += __shfl_xor(sA, o);
        sB += __shfl_xor(sB, o);
      }
      plA[j] = (j < nv) ? sA : -3.0e38f;
      plB[j] = (j < nv) ? sB : -3.0e38f;
    }
    float cmA = fmaxf(fmaxf(plA[0], plA[1]), fmaxf(plA[2], plA[3]));
    float cmB = fmaxf(fmaxf(plB[0], plB[1]), fmaxf(plB[2], plB[3]));
    float mnA = fmaxf(mA, cmA), mnB = fmaxf(mB, cmB);
    if (__any(mnA > mA + 8.f || mnB > mB + 8.f)) {
      float fsA = __expf(mA - mnA), fsB = __expf(mB - mnB);
      dA *= fsA; dB *= fsB;
      #pragma unroll
      for (int c = 0; c < 4; c++) { oA[c] *= fsA; oB[c] *= fsB; }
      mA = mnA; mB = mnB;
    }
    float pA[4], pB[4];
    #pragma unroll
    for (int j = 0; j < 4; j++) { pA[j] = __expf(plA[j] - mA); pB[j] = __expf(plB[j] - mB); }
    dA += (pA[0] + pA[1]) + (pA[2] + pA[3]);
    dB += (pB[0] + pB[1]) + (pB[2] + pB[3]);
    #pragma unroll
    for (int c = 0; c < 4; c++) {
      oA[c] += (pA[0] * xA[0][c] + pA[1] * xA[1][c]) + (pA[2] * xA[2][c] + pA[3] * xA[3][c]);
      oB[c] += (pB[0] * xB[0][c] + pB[1] * xB[1][c]) + (pB[2] * xB[2][c] + pB[3] * xB[3][c]);
    }
  }
  float iA = dA > 0.f ? 1.f / dA : 0.f;
  float iB = dB > 0.f ? 1.f / dB : 0.f;
  float rA[4], rB[4];
  #pragma unroll
  for (int c = 0; c < 4; c++) {
    float vA = oA[c] * iA + bias[ca + c];
    float vB = oB[c] * iB + bias[cb + c];
    rA[c] = vA > 0.f ? vA : 0.f;         // relu after conv1
    rB[c] = vB > 0.f ? vB : 0.f;
  }
  if (H1BF) {
    unsigned short* hb = (unsigned short*)h1out;
    ushort4 ua, ub;
    ua.x = f2b(rA[0]); ua.y = f2b(rA[1]); ua.z = f2b(rA[2]); ua.w = f2b(rA[3]);
    ub.x = f2b(rB[0]); ub.y = f2b(rB[1]); ub.z = f2b(rB[2]); ub.w = f2b(rB[3]);
    *(ushort4*)&hb[(size_t)n * HC1 + ca] = ua;
    *(ushort4*)&hb[(size_t)n * HC1 + cb] = ub;
  } else {
    float* hf = (float*)h1out;
    *(float4*)&hf[(size_t)n * HC1 + ca] = *(float4*)rA;
    *(float4*)&hf[(size_t)n * HC1 + cb] = *(float4*)rB;
  }
}

// ---------------- linear2 ----------------
template<bool INBF>
__global__ __launch_bounds__(256) void linear2_kernel(
    const void* __restrict__ hin_, const float* __restrict__ Wl,
    const float* __restrict__ bl, const float* __restrict__ Wr,
    const float* __restrict__ br, float* __restrict__ xl, float* __restrict__ xr)
{
  __shared__ float xsT[HC1][16];   // 32KB
  int n0 = blockIdx.x * 16;
  int t = threadIdx.x;
  for (int r = 0; r < 8; r++) {
    int flat = (t + r * 256) * 4;
    int i = flat >> 9, k = flat & 511;
    float4 v;
    if (INBF) {
      const unsigned short* hb = (const unsigned short*)hin_;
      ushort4 u = *(const ushort4*)&hb[(size_t)(n0 + i) * HC1 + k];
      v.x = b2f(u.x); v.y = b2f(u.y); v.z = b2f(u.z); v.w = b2f(u.w);
    } else {
      const float* hf = (const float*)hin_;
      v = *(const float4*)&hf[(size_t)(n0 + i) * HC1 + k];
    }
    xsT[k + 0][i] = v.x; xsT[k + 1][i] = v.y; xsT[k + 2][i] = v.z; xsT[k + 3][i] = v.w;
  }
  __syncthreads();
  int m = t >> 7, j = t & 127;
  const float* W = m ? Wr : Wl;
  float bj = (m ? br : bl)[j];
  float* out = m ? xr : xl;
  float acc[16];
  #pragma unroll
  for (int i = 0; i < 16; i++) acc[i] = 0.f;
  for (int k = 0; k < HC1; k++) {
    float w = W[k * HID + j];
    float xv[16];
    *(float4*)&xv[0]  = *(const float4*)&xsT[k][0];
    *(float4*)&xv[4]  = *(const float4*)&xsT[k][4];
    *(float4*)&xv[8]  = *(const float4*)&xsT[k][8];
    *(float4*)&xv[12] = *(const float4*)&xsT[k][12];
    #pragma unroll
    for (int i = 0; i < 16; i++) acc[i] = fmaf(xv[i], w, acc[i]);
  }
  #pragma unroll
  for (int i = 0; i < 16; i++) out[(size_t)(n0 + i) * HID + j] = acc[i] + bj;
}

// ---------------- fused layer 2 + MLP head ----------------
// block = 512 threads = 8 waves = 8 nodes. lane owns channels {lane, 64+lane}.
__global__ __launch_bounds__(512, 2) void fused2_kernel(
    const float* __restrict__ ea, const int* __restrict__ srcs,
    const float* __restrict__ We, const float* __restrict__ att,
    const float* __restrict__ xl, const float* __restrict__ xr,
    const float* __restrict__ bias, const int* __restrict__ offs,
    const int* __restrict__ csr, const float* __restrict__ Wh1,
    const float* __restrict__ bh1, const float* __restrict__ Wh2,
    const float* __restrict__ bh2, float* __restrict__ out)
{
  __shared__ float Ws[EDGE_DIM * HID];      // 16KB
  __shared__ float Wh1T[64 * 132];          // 33.8KB transposed+padded
  __shared__ float h2s[8][HID];             // 4KB
  int t = threadIdx.x;
  for (int i = t * 4; i < EDGE_DIM * HID; i += 2048)
    *(float4*)&Ws[i] = *(const float4*)&We[i];
  for (int i = t; i < HID * 64; i += 512) {
    int k = i >> 6, j = i & 63;
    Wh1T[j * 132 + k] = Wh1[i];
  }
  __syncthreads();
  int wave = t >> 6, lane = t & 63;
  int n = blockIdx.x * 8 + wave;
  float ata = att[lane], atb = att[64 + lane];
  float xra = xr[(size_t)n * HID + lane], xrb = xr[(size_t)n * HID + 64 + lane];
  float oa = 0.f, ob = 0.f;
  float m = -3.0e38f, d = 0.f;
  int beg = offs[n], end = offs[n + 1];
  int ev = 0, sv = 0;
  if (lane < 4 && beg + lane < end) { ev = csr[beg + lane]; sv = srcs[ev]; }
  for (int i0 = beg; i0 < end; i0 += 4) {
    int nv = end - i0; if (nv > 4) nv = 4;
    int earr[4], sarr[4];
    #pragma unroll
    for (int j = 0; j < 4; j++) { earr[j] = __shfl(ev, j); sarr[j] = __shfl(sv, j); }
    float xa[4], xb[4];
    #pragma unroll
    for (int j = 0; j < 4; j++) {
      if (j < nv) {
        const float* p = &xl[(size_t)sarr[j] * HID];
        xa[j] = p[lane]; xb[j] = p[64 + lane];
      } else { xa[j] = 0.f; xb[j] = 0.f; }
    }
    if (lane < 4 && i0 + 4 + lane < end) { ev = csr[i0 + 4 + lane]; sv = srcs[ev]; }
    float aa[4], ab[4];
    #pragma unroll
    for (int j = 0; j < 4; j++) { aa[j] = 0.f; ab[j] = 0.f; }
    #pragma unroll 1
    for (int kk = 0; kk < 8; kk++) {
      float av[4][4];
      #pragma unroll
      for (int j = 0; j < 4; j++)
        *(float4*)&av[j][0] = *(const float4*)&ea[(size_t)earr[j] * EDGE_DIM + kk * 4];
      #pragma unroll
      for (int dk = 0; dk < 4; dk++) {
        float wA = Ws[(kk * 4 + dk) * HID + lane];
        float wB = Ws[(kk * 4 + dk) * HID + 64 + lane];
        #pragma unroll
        for (int j = 0; j < 4; j++) {
          aa[j] = fmaf(av[j][dk], wA, aa[j]);
          ab[j] = fmaf(av[j][dk], wB, ab[j]);
        }
      }
    }
    float pl[4];
    #pragma unroll
    for (int j = 0; j < 4; j++) {
      float za = aa[j] + xa[j] + xra;
      float zb = ab[j] + xb[j] + xrb;
      za = za > 0.f ? za : NEG_SLOPE * za;
      zb = zb > 0.f ? zb : NEG_SLOPE * zb;
      float s = za * ata + zb * atb;
      #pragma unroll
      for (int o = 1; o < 64; o <<= 1) s += __shfl_xor(s, o);
      pl[j] = (j < nv) ? s : -3.0e38f;
    }
    float cm = fmaxf(fmaxf(pl[0], pl[1]), fmaxf(pl[2], pl[3]));
    float mn = fmaxf(m, cm);
    if (__any(mn > m + 8.f)) {
      float fs = __expf(m - mn);
      d *= fs; oa *= fs; ob *= fs;
      m = mn;
    }
    float p[4];
    #pragma unroll
    for (int j = 0; j < 4; j++) p[j] = __expf(pl[j] - m);
    d += (p[0] + p[1]) + (p[2] + p[3]);
    oa += (p[0] * xa[0] + p[1] * xa[1]) + (p[2] * xa[2] + p[3] * xa[3]);
    ob += (p[0] * xb[0] + p[1] * xb[1]) + (p[2] * xb[2] + p[3] * xb[3]);
  }
  float invd = d > 0.f ? 1.f / d : 0.f;
  float va = oa * invd + bias[lane];
  float vb = ob * invd + bias[64 + lane];   // no relu after conv2
  h2s[wave][lane] = va;
  h2s[wave][64 + lane] = vb;
  asm volatile("s_waitcnt lgkmcnt(0)" ::: "memory");
  float tacc = bh1[lane];
  #pragma unroll 8
  for (int k4 = 0; k4 < HID / 4; k4++) {
    float4 hv = *(const float4*)&h2s[wave][k4 * 4];
    float4 wv = *(const float4*)&Wh1T[lane * 132 + k4 * 4];
    tacc = fmaf(hv.x, wv.x, tacc);
    tacc = fmaf(hv.y, wv.y, tacc);
    tacc = fmaf(hv.z, wv.z, tacc);
    tacc = fmaf(hv.w, wv.w, tacc);
  }
  tacc = tacc > 0.f ? tacc : 0.f;
  float2 w2v = *(const float2*)&Wh2[lane * 2];
  float p0 = tacc * w2v.x;
  float p1 = tacc * w2v.y;
  #pragma unroll
  for (int o = 1; o < 64; o <<= 1) { p0 += __shfl_xor(p0, o); p1 += __shfl_xor(p1, o); }
  if (lane == 0) {
    float2 o2 = make_float2(p0 + bh2[0], p1 + bh2[1]);
    *(float2*)&out[(size_t)n * 2] = o2;
  }
}

extern "C" void kernel_launch(void* const* d_in, const int* in_sizes, int n_in,
                              void* d_out, int out_size, void* d_ws, size_t ws_size,
                              hipStream_t stream)
{
  (void)in_sizes; (void)n_in; (void)out_size;
  const float* x    = (const float*)d_in[0];
  const int* eidx   = (const int*)d_in[1];
  const float* ea   = (const float*)d_in[2];
  const float* Wl1  = (const float*)d_in[3];
  const float* bl1  = (const float*)d_in[4];
  const float* Wr1  = (const float*)d_in[5];
  const float* br1  = (const float*)d_in[6];
  const float* We1  = (const float*)d_in[7];
  const float* att1 = (const float*)d_in[8];
  const float* bias1= (const float*)d_in[9];
  const float* Wl2  = (const float*)d_in[10];
  const float* bl2  = (const float*)d_in[11];
  const float* Wr2  = (const float*)d_in[12];
  const float* br2  = (const float*)d_in[13];
  const float* We2  = (const float*)d_in[14];
  const float* att2 = (const float*)d_in[15];
  const float* bias2= (const float*)d_in[16];
  const float* Wh1  = (const float*)d_in[17];
  const float* bh1  = (const float*)d_in[18];
  const float* Wh2  = (const float*)d_in[19];
  const float* bh2  = (const float*)d_in[20];
  const int* srcs = eidx;
  const int* dsts = eidx + N_EDGES;
  float* out = (float*)d_out;

  const size_t szBig = (size_t)N_NODES * HC1 * sizeof(float);
  auto aln = [](size_t b) { return (b + 511) & ~(size_t)511; };
  size_t smallSz = aln((size_t)N_NODES * 4) * 2 + aln((size_t)(N_NODES + 1) * 4)
                 + aln((size_t)N_EDGES * 4);
  size_t needF = aln(szBig) * 3 + smallSz + 4096;
  bool useBF = ws_size < needF;

  char* p = (char*)d_ws;
  auto alloc = [&](size_t bytes) { char* q = p; p += (bytes + 511) & ~(size_t)511; return q; };
  float* xl1 = (float*)alloc(szBig);
  float* xr1 = (float*)alloc(szBig);          // reused for xl2/xr2 after fused1
  void*  h1  = (void*)alloc(useBF ? szBig / 2 : szBig);
  int* deg    = (int*)alloc((size_t)N_NODES * 4);
  int* offs   = (int*)alloc((size_t)(N_NODES + 1) * 4);
  int* cursor = (int*)alloc((size_t)N_NODES * 4);
  int* csr    = (int*)alloc((size_t)N_EDGES * 4);
  float* xl2 = xr1;
  float* xr2 = xr1 + (size_t)N_NODES * HID;

  hipLaunchKernelGGL(zero_deg_kernel, dim3((N_NODES + 255) / 256), dim3(256), 0, stream, deg);
  hipLaunchKernelGGL(deg_count_kernel, dim3((N_EDGES + 255) / 256), dim3(256), 0, stream, dsts, deg);
  hipLaunchKernelGGL(scan_kernel, dim3(1), dim3(1024), 0, stream, deg, offs, cursor);
  hipLaunchKernelGGL(scatter_kernel, dim3((N_EDGES + 255) / 256), dim3(256), 0, stream, dsts, cursor, csr);
  hipLaunchKernelGGL(linear1_kernel, dim3(N_NODES / 16), dim3(256), 0, stream,
                     x, Wl1, bl1, Wr1, br1, xl1, xr1);
  if (useBF)
    hipLaunchKernelGGL((fused1_kernel<true>), dim3(N_NODES / 8), dim3(512), 0, stream,
                       ea, srcs, We1, att1, xl1, xr1, bias1, offs, csr, h1);
  else
    hipLaunchKernelGGL((fused1_kernel<false>), dim3(N_NODES / 8), dim3(512), 0, stream,
                       ea, srcs, We1, att1, xl1, xr1, bias1, offs, csr, h1);
  if (useBF)
    hipLaunchKernelGGL((linear2_kernel<true>), dim3(N_NODES / 16), dim3(256), 0, stream,
                       h1, Wl2, bl2, Wr2, br2, xl2, xr2);
  else
    hipLaunchKernelGGL((linear2_kernel<false>), dim3(N_NODES / 16), dim3(256), 0, stream,
                       h1, Wl2, bl2, Wr2, br2, xl2, xr2);
  hipLaunchKernelGGL(fused2_kernel, dim3(N_NODES / 8), dim3(512), 0, stream,
                     ea, srcs, We2, att2, xl2, xr2, bias2, offs, csr,
                     Wh1, bh1, Wh2, bh2, out);
}